// Round 1
// baseline (268.749 us; speedup 1.0000x reference)
//
#include <hip/hip_runtime.h>
#include <hip/hip_bf16.h>

// Sizes (fixed by the reference)
#define AN 256   // annotators
#define BN 64    // batch
#define DN 768   // hidden
#define LN 2     // labels
#define G1N 4
#define G2N 8
#define NPAIR (G1N * G2N)   // 32

// ---------------------------------------------------------------------------
// Tiled fp32 GEMM: C[64 x 768] = A[64 x 768] * B[768 x 768] + bias
// Each block computes a 64(M) x 64(N) tile. 256 threads = 16x16, 4x4 micro.
// ---------------------------------------------------------------------------
#define KT 16

__device__ __forceinline__ void gemm_tile_64(
    const float* __restrict__ A,    // [64, 768] row-major
    const float* __restrict__ Bm,   // [768, 768] row-major
    const float* __restrict__ bias, // [768]
    float* __restrict__ C,          // [64, 768] row-major
    int e0)                         // N-tile start (0, 64, ..., 704)
{
    __shared__ float As[KT][64 + 1];   // As[k][m]
    __shared__ float Bs[KT][64 + 1];   // Bs[k][e]

    const int tid = threadIdx.x;
    const int tx  = tid & 15;          // 0..15 (col group)
    const int ty  = tid >> 4;          // 0..15 (row group)

    float acc[4][4] = {};

    const int lk  = tid & 15;          // k for A-load
    const int lm  = tid >> 4;          // row base for A-load (0..15)
    const int le  = tid & 63;          // e for B-load
    const int lkb = tid >> 6;          // k base for B-load (0..3)

    for (int k0 = 0; k0 < DN; k0 += KT) {
        // Stage A tile: 64 rows x KT cols
        #pragma unroll
        for (int i = 0; i < 4; ++i) {
            As[lk][lm + 16 * i] = A[(lm + 16 * i) * DN + k0 + lk];
        }
        // Stage B tile: KT rows x 64 cols
        #pragma unroll
        for (int i = 0; i < 4; ++i) {
            Bs[lkb + 4 * i][le] = Bm[(size_t)(k0 + lkb + 4 * i) * DN + e0 + le];
        }
        __syncthreads();

        #pragma unroll
        for (int kk = 0; kk < KT; ++kk) {
            float av[4], bv[4];
            #pragma unroll
            for (int i = 0; i < 4; ++i) av[i] = As[kk][ty * 4 + i];
            #pragma unroll
            for (int j = 0; j < 4; ++j) bv[j] = Bs[kk][tx * 4 + j];
            #pragma unroll
            for (int i = 0; i < 4; ++i)
                #pragma unroll
                for (int j = 0; j < 4; ++j)
                    acc[i][j] += av[i] * bv[j];
        }
        __syncthreads();
    }

    #pragma unroll
    for (int i = 0; i < 4; ++i) {
        int row = ty * 4 + i;
        #pragma unroll
        for (int j = 0; j < 4; ++j) {
            int col = e0 + tx * 4 + j;
            C[(size_t)row * DN + col] = acc[i][j] + bias[col];
        }
    }
}

// Kernel 1: h_g[g] = pooled @ W1[g] + b1[g]   (grid.y = g in [0,4))
__global__ __launch_bounds__(256) void k1_group1(
    const float* __restrict__ pooled, const float* __restrict__ W1,
    const float* __restrict__ b1, float* __restrict__ h_g)
{
    int e0 = blockIdx.x * 64;
    int g  = blockIdx.y;
    gemm_tile_64(pooled,
                 W1 + (size_t)g * DN * DN,
                 b1 + (size_t)g * DN,
                 h_g + (size_t)g * BN * DN,
                 e0);
}

// Kernel 2: h2[p] = h_g[p/8] @ W2[p%8] + b2[p%8]   (grid.y = p in [0,32))
__global__ __launch_bounds__(256) void k2_pairs(
    const float* __restrict__ h_g, const float* __restrict__ W2,
    const float* __restrict__ b2, float* __restrict__ h2)
{
    int e0 = blockIdx.x * 64;
    int p  = blockIdx.y;
    int g1 = p >> 3;   // p / 8
    int g2 = p & 7;    // p % 8
    gemm_tile_64(h_g + (size_t)g1 * BN * DN,
                 W2 + (size_t)g2 * DN * DN,
                 b2 + (size_t)g2 * DN,
                 h2 + (size_t)p * BN * DN,
                 e0);
}

// Kernel 3: out[b, a, l] = h2[pair(a)][b, :] . Wh[a][:, l] + bh[a, l]
// One block (256 thr = 4 waves) per annotator; each wave handles 16 b's.
__global__ __launch_bounds__(256) void k3_heads(
    const float* __restrict__ h2, const float* __restrict__ Wh,
    const float* __restrict__ bh, const int* __restrict__ g1_idx,
    const int* __restrict__ g2_idx, float* __restrict__ out)
{
    __shared__ float wsh[DN * LN];   // Wh[a] staged: wsh[d*2 + l]

    const int a = blockIdx.x;
    const int pair = g1_idx[a] * G2N + g2_idx[a];
    const float* __restrict__ H = h2 + (size_t)pair * BN * DN;

    for (int i = threadIdx.x; i < DN * LN; i += 256)
        wsh[i] = Wh[(size_t)a * DN * LN + i];
    __syncthreads();

    const int wave = threadIdx.x >> 6;
    const int lane = threadIdx.x & 63;
    const float bh0 = bh[a * LN + 0];
    const float bh1 = bh[a * LN + 1];

    for (int b = wave; b < BN; b += 4) {
        const float* __restrict__ hr = H + (size_t)b * DN;
        float acc0 = 0.f, acc1 = 0.f;
        #pragma unroll
        for (int d = lane; d < DN; d += 64) {
            float x = hr[d];
            acc0 += x * wsh[d * 2 + 0];
            acc1 += x * wsh[d * 2 + 1];
        }
        #pragma unroll
        for (int off = 32; off > 0; off >>= 1) {
            acc0 += __shfl_down(acc0, off, 64);
            acc1 += __shfl_down(acc1, off, 64);
        }
        if (lane == 0) {
            out[(size_t)b * (AN * LN) + a * LN + 0] = acc0 + bh0;
            out[(size_t)b * (AN * LN) + a * LN + 1] = acc1 + bh1;
        }
    }
}

extern "C" void kernel_launch(void* const* d_in, const int* in_sizes, int n_in,
                              void* d_out, int out_size, void* d_ws, size_t ws_size,
                              hipStream_t stream) {
    const float* pooled = (const float*)d_in[0];   // [64, 768]
    const float* W1     = (const float*)d_in[1];   // [4, 768, 768]
    const float* b1     = (const float*)d_in[2];   // [4, 768]
    const float* W2     = (const float*)d_in[3];   // [8, 768, 768]
    const float* b2     = (const float*)d_in[4];   // [8, 768]
    const float* Wh     = (const float*)d_in[5];   // [256, 768, 2]
    const float* bh     = (const float*)d_in[6];   // [256, 2]
    const int*   g1i    = (const int*)d_in[7];     // [256]
    const int*   g2i    = (const int*)d_in[8];     // [256]
    float* out = (float*)d_out;                    // [64, 256, 2]

    // Workspace layout: h_g [4*64*768] then h2 [32*64*768] (fp32)
    float* h_g = (float*)d_ws;
    float* h2  = h_g + (size_t)G1N * BN * DN;

    dim3 blk(256);
    k1_group1<<<dim3(DN / 64, G1N), blk, 0, stream>>>(pooled, W1, b1, h_g);
    k2_pairs <<<dim3(DN / 64, NPAIR), blk, 0, stream>>>(h_g, W2, b2, h2);
    k3_heads <<<dim3(AN), blk, 0, stream>>>(h2, Wh, bh, g1i, g2i, out);
}

// Round 2
// 194.561 us; speedup vs baseline: 1.3813x; 1.3813x over previous
//
#include <hip/hip_runtime.h>
#include <hip/hip_bf16.h>

#define AN 256   // annotators
#define BN 64    // batch
#define DN 768   // hidden
#define LN 2     // labels
#define G1N 4
#define G2N 8
#define NPAIR (G1N * G2N)   // 32

typedef __attribute__((ext_vector_type(8))) short short8;   // 8 bf16 (4 VGPRs)
typedef __attribute__((ext_vector_type(4))) float floatx4;  // MFMA acc

static __device__ __forceinline__ unsigned short f2bf(float f) {
    union { float f; unsigned int u; } v; v.f = f;
    unsigned int r = v.u + 0x7FFF + ((v.u >> 16) & 1);  // RNE (finite inputs)
    return (unsigned short)(r >> 16);
}

// ---------------------------------------------------------------------------
// Prep: convert pooled -> bf16; transpose+convert W1,W2 -> Wt[e][d] bf16.
// grid = (144, 13). y in [0,4): W1 group y. y in [4,12): W2 group y-4.
// y == 12: pooled convert (x in [0,12) only).
// ---------------------------------------------------------------------------
__global__ __launch_bounds__(256) void k0_prep(
    const float* __restrict__ W1, const float* __restrict__ W2,
    const float* __restrict__ pooled,
    unsigned short* __restrict__ W1t, unsigned short* __restrict__ W2t,
    unsigned short* __restrict__ pooled_bf)
{
    const int tid = threadIdx.x;
    const int r = tid >> 4;          // 0..15
    const int c = (tid & 15) * 4;    // 0..60 step 4

    if (blockIdx.y == 12) {
        if (blockIdx.x >= 12) return;
        int c0 = blockIdx.x * 64;
        #pragma unroll
        for (int i = 0; i < 4; ++i) {
            int row = r + 16 * i;
            const float* s = pooled + (size_t)row * DN + c0 + c;
            unsigned short* d = pooled_bf + (size_t)row * DN + c0 + c;
            #pragma unroll
            for (int j = 0; j < 4; ++j) d[j] = f2bf(s[j]);
        }
        return;
    }

    const int y = blockIdx.y;
    const float* src = (y < 4) ? (W1 + (size_t)y * DN * DN)
                               : (W2 + (size_t)(y - 4) * DN * DN);
    unsigned short* dst = (y < 4) ? (W1t + (size_t)y * DN * DN)
                                  : (W2t + (size_t)(y - 4) * DN * DN);
    const int d0 = (blockIdx.x / 12) * 64;
    const int e0 = (blockIdx.x % 12) * 64;

    __shared__ float tile[64][65];
    #pragma unroll
    for (int i = 0; i < 4; ++i) {
        const float* s = src + (size_t)(d0 + r + 16 * i) * DN + e0 + c;
        #pragma unroll
        for (int j = 0; j < 4; ++j) tile[r + 16 * i][c + j] = s[j];
    }
    __syncthreads();
    // dst[e][d] = src[d][e]
    #pragma unroll
    for (int i = 0; i < 4; ++i) {
        unsigned short* d = dst + (size_t)(e0 + r + 16 * i) * DN + d0 + c;
        #pragma unroll
        for (int j = 0; j < 4; ++j) d[j] = f2bf(tile[c + j][r + 16 * i]);
    }
}

// ---------------------------------------------------------------------------
// MFMA GEMM: C[64 x 64-tile] = Abf[64 x 768] @ Wt^T (+bias)
// Wt is [768(e)][768(d)] bf16 (pre-transposed weight). 4 waves; wave w owns
// e-strip e0+w*16 across all M=64 (4 mfma C-frags). Direct-from-global frags:
// A lane reads A[m=mt*16+(lane&15)][d0+quad*8 ..+8] (16B contiguous);
// B lane reads Wt[e0+w*16+(lane&15)][d0+quad*8 ..+8] (16B contiguous).
// ---------------------------------------------------------------------------
template<bool STORE_BF16>
__device__ __forceinline__ void mfma_gemm64(
    const unsigned short* __restrict__ Abf,   // [64][768] bf16
    const unsigned short* __restrict__ Wt,    // [768][768] bf16: Wt[e][d]
    const float* __restrict__ bias,           // [768]
    void* __restrict__ Cout,                  // [64][768] bf16 or fp32
    int e0)
{
    const int lane = threadIdx.x & 63;
    const int wave = threadIdx.x >> 6;
    const int n    = lane & 15;
    const int quad = lane >> 4;
    const int e    = e0 + wave * 16 + n;

    floatx4 acc[4] = {{0,0,0,0},{0,0,0,0},{0,0,0,0},{0,0,0,0}};

    const unsigned short* aBase = Abf + (size_t)n * DN + quad * 8;
    const unsigned short* bBase = Wt + (size_t)e * DN + quad * 8;

    for (int d0 = 0; d0 < DN; d0 += 32) {
        short8 bf = *(const short8*)(bBase + d0);
        #pragma unroll
        for (int mt = 0; mt < 4; ++mt) {
            short8 af = *(const short8*)(aBase + (size_t)mt * 16 * DN + d0);
            acc[mt] = __builtin_amdgcn_mfma_f32_16x16x32_bf16(af, bf, acc[mt], 0, 0, 0);
        }
    }

    const float bv = bias[e];
    #pragma unroll
    for (int mt = 0; mt < 4; ++mt) {
        #pragma unroll
        for (int r = 0; r < 4; ++r) {
            int m = mt * 16 + quad * 4 + r;   // C row = (lane>>4)*4 + reg
            float v = acc[mt][r] + bv;
            if (STORE_BF16)
                ((unsigned short*)Cout)[(size_t)m * DN + e] = f2bf(v);
            else
                ((float*)Cout)[(size_t)m * DN + e] = v;
        }
    }
}

// Kernel 1: h_g[g] = pooled @ W1[g] + b1[g]  -> bf16
__global__ __launch_bounds__(256) void k1_mfma(
    const unsigned short* __restrict__ pooled_bf,
    const unsigned short* __restrict__ W1t,
    const float* __restrict__ b1, unsigned short* __restrict__ h_g)
{
    mfma_gemm64<true>(pooled_bf, W1t + (size_t)blockIdx.y * DN * DN,
                      b1 + blockIdx.y * DN,
                      h_g + (size_t)blockIdx.y * BN * DN, blockIdx.x * 64);
}

// Kernel 2: h2[p] = h_g[p>>3] @ W2[p&7] + b2[p&7]  -> fp32
__global__ __launch_bounds__(256) void k2_mfma(
    const unsigned short* __restrict__ h_g,
    const unsigned short* __restrict__ W2t,
    const float* __restrict__ b2, float* __restrict__ h2)
{
    int p = blockIdx.y;
    mfma_gemm64<false>(h_g + (size_t)(p >> 3) * BN * DN,
                       W2t + (size_t)(p & 7) * DN * DN,
                       b2 + (p & 7) * DN,
                       h2 + (size_t)p * BN * DN, blockIdx.x * 64);
}

// Kernel 3: out[b, a, l] = h2[pair(a)][b, :] . Wh[a][:, l] + bh[a, l]
__global__ __launch_bounds__(256) void k3_heads(
    const float* __restrict__ h2, const float* __restrict__ Wh,
    const float* __restrict__ bh, const int* __restrict__ g1_idx,
    const int* __restrict__ g2_idx, float* __restrict__ out)
{
    __shared__ float wsh[DN * LN];

    const int a = blockIdx.x;
    const int pair = g1_idx[a] * G2N + g2_idx[a];
    const float* __restrict__ H = h2 + (size_t)pair * BN * DN;

    for (int i = threadIdx.x; i < DN * LN; i += 256)
        wsh[i] = Wh[(size_t)a * DN * LN + i];
    __syncthreads();

    const int wave = threadIdx.x >> 6;
    const int lane = threadIdx.x & 63;
    const float bh0 = bh[a * LN + 0];
    const float bh1 = bh[a * LN + 1];

    for (int b = wave; b < BN; b += 4) {
        const float* __restrict__ hr = H + (size_t)b * DN;
        float acc0 = 0.f, acc1 = 0.f;
        #pragma unroll
        for (int d = lane; d < DN; d += 64) {
            float x = hr[d];
            acc0 += x * wsh[d * 2 + 0];
            acc1 += x * wsh[d * 2 + 1];
        }
        #pragma unroll
        for (int off = 32; off > 0; off >>= 1) {
            acc0 += __shfl_down(acc0, off, 64);
            acc1 += __shfl_down(acc1, off, 64);
        }
        if (lane == 0) {
            out[(size_t)b * (AN * LN) + a * LN + 0] = acc0 + bh0;
            out[(size_t)b * (AN * LN) + a * LN + 1] = acc1 + bh1;
        }
    }
}

extern "C" void kernel_launch(void* const* d_in, const int* in_sizes, int n_in,
                              void* d_out, int out_size, void* d_ws, size_t ws_size,
                              hipStream_t stream) {
    const float* pooled = (const float*)d_in[0];
    const float* W1     = (const float*)d_in[1];
    const float* b1     = (const float*)d_in[2];
    const float* W2     = (const float*)d_in[3];
    const float* b2     = (const float*)d_in[4];
    const float* Wh     = (const float*)d_in[5];
    const float* bh     = (const float*)d_in[6];
    const int*   g1i    = (const int*)d_in[7];
    const int*   g2i    = (const int*)d_in[8];
    float* out = (float*)d_out;

    // Workspace carve (bytes): W1t | W2t | pooled_bf | h_g | h2  (~20 MB)
    char* ws = (char*)d_ws;
    unsigned short* W1t = (unsigned short*)ws;                  ws += (size_t)G1N * DN * DN * 2;
    unsigned short* W2t = (unsigned short*)ws;                  ws += (size_t)G2N * DN * DN * 2;
    unsigned short* pooled_bf = (unsigned short*)ws;            ws += (size_t)BN * DN * 2;
    unsigned short* h_g = (unsigned short*)ws;                  ws += (size_t)G1N * BN * DN * 2;
    float* h2 = (float*)ws;

    dim3 blk(256);
    k0_prep<<<dim3(144, 13), blk, 0, stream>>>(W1, W2, pooled, W1t, W2t, pooled_bf);
    k1_mfma<<<dim3(DN / 64, G1N), blk, 0, stream>>>(pooled_bf, W1t, b1, h_g);
    k2_mfma<<<dim3(DN / 64, NPAIR), blk, 0, stream>>>(h_g, W2t, b2, h2);
    k3_heads<<<dim3(AN), blk, 0, stream>>>(h2, Wh, bh, g1i, g2i, out);
}